// Round 2
// baseline (52.315 us; speedup 1.0000x reference)
//
#include <hip/hip_runtime.h>

#define D_DIM 4096
#define H_DIM 4096
#define HB 16               // rows (h) per block
#define IB 1024             // columns per tile
#define NSEG (IB / 256)     // 4 float4-segments per lane per tile
#define SP (IB + 4)         // padded LDS stride (16B aligned)
#define NT (D_DIM / IB)     // 4 tiles
#define NBLK (H_DIM / HB)   // 256 blocks

__device__ __forceinline__ float fast_sigmoid(float a) {
    return __builtin_amdgcn_rcpf(1.0f + __expf(-a));
}

// Grid: NBLK x 1024 threads (16 waves). Wave wv owns row h0+wv's prefix scan.
// Per tile: scan phase (w loads + interleaved wave scans + sigmoid -> LDS),
// reduce phase (v loads + LDS dot -> coalesced part store). Deep prefetch:
// w(t+1) issued pre-barrier, v(t+1) issued post-barrier (overlaps reduce t).
template <bool ATOMIC>
__global__ __launch_bounds__(1024, 4) void nade_main_kernel(
    const float* __restrict__ x,
    const float* __restrict__ w,
    const float* __restrict__ v,
    const float* __restrict__ c,
    float* __restrict__ part)
{
    __shared__ float S[HB][SP];   // 16 x 1028 x 4B = 65.8 KB, single-buffered

    const int tid  = threadIdx.x;
    const int wv   = tid >> 6;
    const int lane = tid & 63;
    const int h0   = blockIdx.x * HB;
    const int h    = h0 + wv;
    const float* wrow = w + (size_t)h * D_DIM;

    float carry = c[h];

    float4 wp[NSEG], wn[NSEG], vp[4], vn[4];

    auto load_w = [&](int t, float4* dst) {
        const float* p = wrow + t * IB + 4 * lane;
        #pragma unroll
        for (int s = 0; s < NSEG; ++s)
            dst[s] = *reinterpret_cast<const float4*>(p + s * 256);
    };
    auto load_v = [&](int t, float4* dst) {
        // thread owns column i = t*IB + tid; reads 64 contiguous bytes of v[i, h0..h0+15]
        const float* p = v + ((size_t)(t * IB + tid)) * H_DIM + h0;
        #pragma unroll
        for (int k = 0; k < 4; ++k)
            dst[k] = *reinterpret_cast<const float4*>(p + 4 * k);
    };

    load_w(0, wp);
    load_v(0, vp);

    for (int t = 0; t < NT; ++t) {
        // ---- scan phase: 1024 columns, 4 interleaved 64-lane scans ----
        float4 xp[NSEG];
        {
            const float* p = x + t * IB + 4 * lane;
            #pragma unroll
            for (int s = 0; s < NSEG; ++s)
                xp[s] = *reinterpret_cast<const float4*>(p + s * 256);
        }
        float pr[NSEG][4], sum4[NSEG], incl[NSEG];
        #pragma unroll
        for (int s = 0; s < NSEG; ++s) {
            pr[s][0] = wp[s].x * xp[s].x;
            pr[s][1] = wp[s].y * xp[s].y;
            pr[s][2] = wp[s].z * xp[s].z;
            pr[s][3] = wp[s].w * xp[s].w;
            sum4[s] = pr[s][0] + pr[s][1] + pr[s][2] + pr[s][3];
            incl[s] = sum4[s];
        }
        #pragma unroll
        for (int off = 1; off < 64; off <<= 1) {
            #pragma unroll
            for (int s = 0; s < NSEG; ++s) {
                float tv = __shfl_up(incl[s], off, 64);
                incl[s] += (lane >= off) ? tv : 0.0f;
            }
        }
        float base = carry;
        #pragma unroll
        for (int s = 0; s < NSEG; ++s) {
            float tot = __shfl(incl[s], 63, 64);
            float a0 = base + incl[s] - sum4[s];   // exclusive prefix + carry
            float a1 = a0 + pr[s][0];
            float a2 = a1 + pr[s][1];
            float a3 = a2 + pr[s][2];
            float4 sv;
            sv.x = fast_sigmoid(a0);
            sv.y = fast_sigmoid(a1);
            sv.z = fast_sigmoid(a2);
            sv.w = fast_sigmoid(a3);
            *reinterpret_cast<float4*>(&S[wv][s * 256 + 4 * lane]) = sv;
            base += tot;
        }
        carry = base;

        if (t + 1 < NT) load_w(t + 1, wn);   // prefetch next w (HBM) pre-barrier
        __syncthreads();
        if (t + 1 < NT) load_v(t + 1, vn);   // prefetch next v, overlaps reduce

        // ---- reduce phase: thread owns column i, dots v[i, h0:h0+16] with S ----
        float acc = 0.0f;
        #pragma unroll
        for (int k = 0; k < 4; ++k) {
            acc += vp[k].x * S[4 * k + 0][tid]
                 + vp[k].y * S[4 * k + 1][tid]
                 + vp[k].z * S[4 * k + 2][tid]
                 + vp[k].w * S[4 * k + 3][tid];
        }
        const int i = t * IB + tid;
        if (ATOMIC) atomicAdd(&part[i], acc);
        else        part[(size_t)blockIdx.x * D_DIM + i] = acc;

        __syncthreads();   // S reads done before next scan overwrites
        #pragma unroll
        for (int s = 0; s < NSEG; ++s) wp[s] = wn[s];
        #pragma unroll
        for (int k = 0; k < 4; ++k) vp[k] = vn[k];
    }
}

// Grid: D/64 blocks x 1024 threads. Sums the [NBLK][D] partial matrix (coalesced).
__global__ __launch_bounds__(1024, 1) void nade_reduce_kernel(
    const float* __restrict__ part,
    const float* __restrict__ b,
    float* __restrict__ out)
{
    __shared__ float red[16][64];
    const int tid = threadIdx.x;
    const int bg  = tid >> 6;      // wave id 0..15
    const int il  = tid & 63;
    const int i   = blockIdx.x * 64 + il;
    float s = 0.0f;
    #pragma unroll
    for (int j = 0; j < NBLK / 16; ++j)
        s += part[(size_t)(bg * (NBLK / 16) + j) * D_DIM + i];
    red[bg][il] = s;
    __syncthreads();
    if (tid < 64) {
        float t = b[blockIdx.x * 64 + tid];
        #pragma unroll
        for (int j = 0; j < 16; ++j) t += red[j][tid];
        out[blockIdx.x * 64 + tid] = fast_sigmoid(t);
    }
}

__global__ __launch_bounds__(256, 1) void nade_final_atomic(
    const float* __restrict__ logits,
    const float* __restrict__ b,
    float* __restrict__ out)
{
    const int i = blockIdx.x * 256 + threadIdx.x;
    out[i] = fast_sigmoid(logits[i] + b[i]);
}

extern "C" void kernel_launch(void* const* d_in, const int* in_sizes, int n_in,
                              void* d_out, int out_size, void* d_ws, size_t ws_size,
                              hipStream_t stream)
{
    const float* x = (const float*)d_in[0];
    const float* w = (const float*)d_in[1];
    const float* b = (const float*)d_in[2];
    const float* v = (const float*)d_in[3];
    const float* c = (const float*)d_in[4];
    float* out = (float*)d_out;
    float* ws  = (float*)d_ws;

    const size_t need = (size_t)NBLK * D_DIM * sizeof(float);
    if (ws_size >= need) {
        nade_main_kernel<false><<<NBLK, 1024, 0, stream>>>(x, w, v, c, ws);
        nade_reduce_kernel<<<D_DIM / 64, 1024, 0, stream>>>(ws, b, out);
    } else {
        hipMemsetAsync(d_ws, 0, D_DIM * sizeof(float), stream);
        nade_main_kernel<true><<<NBLK, 1024, 0, stream>>>(x, w, v, c, ws);
        nade_final_atomic<<<D_DIM / 256, 256, 0, stream>>>(ws, b, out);
    }
}